// Round 1
// baseline (213.264 us; speedup 1.0000x reference)
//
#include <hip/hip_runtime.h>

// Problem constants
constexpr int B_ = 32, C_ = 64, H_ = 64, W_ = 64, K_ = 1024;
constexpr int NTOT = B_ * C_ * H_ * W_;          // 8388608 elements of input1/quantized
constexpr int NSP  = B_ * H_ * W_;               // 131072 spatial positions
// d_out float offsets: [0]=loss, [1..32]=input2_KL, [33..33+NTOT)=quantized(BCHW),
// [OFF_ENC .. OFF_ENC+NSP*K)=encodings
constexpr int OFF_Q   = 33;
constexpr int OFF_ENC = OFF_Q + NTOT;            // 8388641  (== 1 mod 4: misaligned!)
constexpr long long ENC_ELEMS = (long long)NSP * K_;   // 134217728
constexpr int ENC_A0  = OFF_ENC + 3;             // 8388644: first 16B-aligned dword
constexpr int ENC_NV4 = (int)((ENC_ELEMS - 4) / 4);    // 33554431 aligned float4 groups

// Main fused kernel: gather codebook rows, write quantized (BCHW), accumulate loss.
__global__ __launch_bounds__(256) void vq_main(const float* __restrict__ input1,
                                               const int*   __restrict__ x_tilde,
                                               const float* __restrict__ weight,
                                               float* __restrict__ out,   // d_out base
                                               float* __restrict__ acc) { // d_ws accumulator
    float local = 0.f;
    const int stride = gridDim.x * blockDim.x;
    for (int f = blockIdx.x * blockDim.x + threadIdx.x; f < NTOT; f += stride) {
        const int b  = f >> 18;          // C*H*W = 2^18
        const int c  = (f >> 12) & 63;   // H*W   = 2^12
        const int hw = f & 4095;
        const int n  = (b << 12) | hw;   // spatial index b*H*W + h*W + w
        const int t  = x_tilde[n];
        const float q  = weight[(t << 6) | c];
        const float xv = input1[f];
        const float d  = q - xv;
        out[OFF_Q + f] = xv + d;         // straight-through: x + (q - x)
        local += d * d;
    }
    // wave64 reduce
    for (int o = 32; o > 0; o >>= 1) local += __shfl_down(local, o);
    __shared__ float sm[4];
    const int lane = threadIdx.x & 63, wid = threadIdx.x >> 6;
    if (lane == 0) sm[wid] = local;
    __syncthreads();
    if (threadIdx.x == 0) {
        atomicAdd(acc, sm[0] + sm[1] + sm[2] + sm[3]);
    }
}

// Finalize: loss scalar + passthrough of input2_KL
__global__ void vq_fin(const float* __restrict__ acc,
                       const float* __restrict__ kl,
                       float* __restrict__ out) {
    const int t = threadIdx.x;
    if (t == 32) out[0] = 1.25f * (*acc) / (float)NTOT;
    if (t < 32)  out[1 + t] = kl[t];
}

// Encodings: one-hot(x_tilde) over [NSP, K]. Aligned float4 interior + scalar edges.
__global__ __launch_bounds__(256) void vq_enc(const int* __restrict__ x_tilde,
                                              float* __restrict__ out) {
    const int stride = gridDim.x * blockDim.x;
    for (int g = blockIdx.x * blockDim.x + threadIdx.x; g < ENC_NV4; g += stride) {
        const int a  = ENC_A0 + 4 * g;        // dword offset in d_out (16B aligned)
        const int e0 = a - OFF_ENC;           // element index within encodings
        const int n  = e0 >> 10;
        const int k0 = e0 & 1023;
        float4 v = make_float4(0.f, 0.f, 0.f, 0.f);
        if (k0 <= 1020) {                     // all 4 elements in one row (common case)
            const int t = x_tilde[n];
            v.x = (t == k0    ) ? 1.f : 0.f;
            v.y = (t == k0 + 1) ? 1.f : 0.f;
            v.z = (t == k0 + 2) ? 1.f : 0.f;
            v.w = (t == k0 + 3) ? 1.f : 0.f;
        } else {                              // crosses a row boundary
            float* vp = reinterpret_cast<float*>(&v);
            #pragma unroll
            for (int j = 0; j < 4; ++j) {
                const int e  = e0 + j;
                const int nn = e >> 10;
                const int kk = e & 1023;
                vp[j] = (x_tilde[nn] == kk) ? 1.f : 0.f;
            }
        }
        *reinterpret_cast<float4*>(out + a) = v;
    }
    if (blockIdx.x == 0 && threadIdx.x == 0) {
        // head: elements 0..2 of row 0; tail: element 1023 of last row
        const int t0 = x_tilde[0];
        out[OFF_ENC + 0] = (t0 == 0) ? 1.f : 0.f;
        out[OFF_ENC + 1] = (t0 == 1) ? 1.f : 0.f;
        out[OFF_ENC + 2] = (t0 == 2) ? 1.f : 0.f;
        const int tl = x_tilde[NSP - 1];
        out[OFF_ENC + (int)ENC_ELEMS - 1] = (tl == 1023) ? 1.f : 0.f;
    }
}

extern "C" void kernel_launch(void* const* d_in, const int* in_sizes, int n_in,
                              void* d_out, int out_size, void* d_ws, size_t ws_size,
                              hipStream_t stream) {
    const float* input1 = (const float*)d_in[0];
    const float* kl     = (const float*)d_in[1];
    const float* weight = (const float*)d_in[2];
    const int*   x_til  = (const int*)d_in[3];
    float* out = (float*)d_out;
    float* acc = (float*)d_ws;

    hipMemsetAsync(acc, 0, sizeof(float), stream);

    vq_main<<<2048, 256, 0, stream>>>(input1, x_til, weight, out, acc);
    vq_fin<<<1, 64, 0, stream>>>(acc, kl, out);
    vq_enc<<<2048, 256, 0, stream>>>(x_til, out);
}

// Round 2
// 186.105 us; speedup vs baseline: 1.1459x; 1.1459x over previous
//
#include <hip/hip_runtime.h>

// Problem constants
constexpr int B_ = 32, C_ = 64, H_ = 64, W_ = 64, K_ = 1024;
constexpr int NTOT = B_ * C_ * H_ * W_;          // 8388608 elements of input1/quantized
constexpr int NSP  = B_ * H_ * W_;               // 131072 spatial positions
// d_out float offsets: [0]=loss, [1..32]=input2_KL, [33..33+NTOT)=quantized(BCHW),
// [OFF_ENC .. OFF_ENC+NSP*K)=encodings
constexpr int OFF_Q   = 33;
constexpr int OFF_ENC = OFF_Q + NTOT;            // 8388641
constexpr long long ENC_ELEMS = (long long)NSP * K_;   // 134217728
constexpr size_t ENC_BYTES = (size_t)ENC_ELEMS * sizeof(float);  // 536870912

// Main fused kernel: gather codebook rows, write quantized (BCHW), accumulate loss.
// 4 elements per thread along hw: a 4-group at f=4g never crosses a c (4096) boundary,
// so x_tilde loads are an aligned int4 and input1 an aligned float4. Stores stay
// scalar (out+33 is 1 mod 4 dwords -> float4 store would be misaligned).
__global__ __launch_bounds__(256) void vq_main(const float* __restrict__ input1,
                                               const int*   __restrict__ x_tilde,
                                               const float* __restrict__ weight,
                                               float* __restrict__ out,   // d_out base
                                               float* __restrict__ acc) { // d_ws accumulator
    float local = 0.f;
    const int stride = gridDim.x * blockDim.x;
    constexpr int NG = NTOT / 4;
    for (int g = blockIdx.x * blockDim.x + threadIdx.x; g < NG; g += stride) {
        const int f  = g << 2;
        const int b  = f >> 18;          // C*H*W = 2^18
        const int c  = (f >> 12) & 63;   // H*W   = 2^12
        const int n0 = (b << 12) | (f & 4095);   // spatial index, multiple of 4
        const int4   t4 = *reinterpret_cast<const int4*>(x_tilde + n0);
        const float4 x4 = *reinterpret_cast<const float4*>(input1 + f);
        const float q0 = weight[(t4.x << 6) | c];
        const float q1 = weight[(t4.y << 6) | c];
        const float q2 = weight[(t4.z << 6) | c];
        const float q3 = weight[(t4.w << 6) | c];
        const float d0 = q0 - x4.x, d1 = q1 - x4.y, d2 = q2 - x4.z, d3 = q3 - x4.w;
        __builtin_nontemporal_store(x4.x + d0, out + OFF_Q + f + 0);
        __builtin_nontemporal_store(x4.y + d1, out + OFF_Q + f + 1);
        __builtin_nontemporal_store(x4.z + d2, out + OFF_Q + f + 2);
        __builtin_nontemporal_store(x4.w + d3, out + OFF_Q + f + 3);
        local += d0 * d0 + d1 * d1 + d2 * d2 + d3 * d3;
    }
    // wave64 reduce
    for (int o = 32; o > 0; o >>= 1) local += __shfl_down(local, o);
    __shared__ float sm[4];
    const int lane = threadIdx.x & 63, wid = threadIdx.x >> 6;
    if (lane == 0) sm[wid] = local;
    __syncthreads();
    if (threadIdx.x == 0) {
        atomicAdd(acc, sm[0] + sm[1] + sm[2] + sm[3]);
    }
}

// Scatter the NSP ones into the (already-zeroed) encodings region, plus finalize
// loss scalar and the input2_KL passthrough in the last block.
__global__ __launch_bounds__(256) void vq_scatter_fin(const int* __restrict__ x_tilde,
                                                      const float* __restrict__ acc,
                                                      const float* __restrict__ kl,
                                                      float* __restrict__ out) {
    const int bid = blockIdx.x;
    if (bid < NSP / 256) {
        const int n = (bid << 8) + threadIdx.x;
        const int t = x_tilde[n];
        out[OFF_ENC + (n << 10) + t] = 1.0f;
    } else {
        const int tt = threadIdx.x;
        if (tt < 32) out[1 + tt] = kl[tt];
        if (tt == 32) out[0] = 1.25f * (*acc) / (float)NTOT;
    }
}

extern "C" void kernel_launch(void* const* d_in, const int* in_sizes, int n_in,
                              void* d_out, int out_size, void* d_ws, size_t ws_size,
                              hipStream_t stream) {
    const float* input1 = (const float*)d_in[0];
    const float* kl     = (const float*)d_in[1];
    const float* weight = (const float*)d_in[2];
    const int*   x_til  = (const int*)d_in[3];
    float* out = (float*)d_out;
    float* acc = (float*)d_ws;

    hipMemsetAsync(acc, 0, sizeof(float), stream);
    // Zero the 537 MB encodings region via the rocclr fill path (~6.9 TB/s measured).
    hipMemsetAsync(out + OFF_ENC, 0, ENC_BYTES, stream);

    vq_main<<<2048, 256, 0, stream>>>(input1, x_til, weight, out, acc);
    vq_scatter_fin<<<NSP / 256 + 1, 256, 0, stream>>>(x_til, acc, kl, out);
}

// Round 3
// 182.082 us; speedup vs baseline: 1.1712x; 1.0221x over previous
//
#include <hip/hip_runtime.h>

// Problem constants
constexpr int B_ = 32, C_ = 64, H_ = 64, W_ = 64, K_ = 1024;
constexpr int NTOT = B_ * C_ * H_ * W_;          // 8388608 elements of input1/quantized
constexpr int NSP  = B_ * H_ * W_;               // 131072 spatial positions
// d_out float offsets: [0]=loss, [1..32]=input2_KL, [33..33+NTOT)=quantized(BCHW),
// [OFF_ENC .. OFF_ENC+NSP*K)=encodings
constexpr int OFF_Q   = 33;
constexpr int OFF_ENC = OFF_Q + NTOT;            // 8388641  (byte addr == 4 mod 16!)
constexpr long long ENC_ELEMS = (long long)NSP * K_;   // 134217728
// 16B-aligned interior of the encodings region: skip 3 head floats, 1 tail float.
// base (OFF_ENC+3)*4 is 16B-aligned; size (ENC_ELEMS-4)*4 is a multiple of 16.
constexpr size_t ENC_FILL_BYTES = (size_t)(ENC_ELEMS - 4) * sizeof(float);

// Main fused kernel: gather codebook rows, write quantized (BCHW), accumulate loss.
__global__ __launch_bounds__(256) void vq_main(const float* __restrict__ input1,
                                               const int*   __restrict__ x_tilde,
                                               const float* __restrict__ weight,
                                               float* __restrict__ out,   // d_out base
                                               float* __restrict__ acc) { // d_ws accumulator
    float local = 0.f;
    const int stride = gridDim.x * blockDim.x;
    constexpr int NG = NTOT / 4;
    for (int g = blockIdx.x * blockDim.x + threadIdx.x; g < NG; g += stride) {
        const int f  = g << 2;
        const int b  = f >> 18;          // C*H*W = 2^18
        const int c  = (f >> 12) & 63;   // H*W   = 2^12
        const int n0 = (b << 12) | (f & 4095);   // spatial index, multiple of 4
        const int4   t4 = *reinterpret_cast<const int4*>(x_tilde + n0);
        const float4 x4 = *reinterpret_cast<const float4*>(input1 + f);
        const float q0 = weight[(t4.x << 6) | c];
        const float q1 = weight[(t4.y << 6) | c];
        const float q2 = weight[(t4.z << 6) | c];
        const float q3 = weight[(t4.w << 6) | c];
        const float d0 = q0 - x4.x, d1 = q1 - x4.y, d2 = q2 - x4.z, d3 = q3 - x4.w;
        __builtin_nontemporal_store(x4.x + d0, out + OFF_Q + f + 0);
        __builtin_nontemporal_store(x4.y + d1, out + OFF_Q + f + 1);
        __builtin_nontemporal_store(x4.z + d2, out + OFF_Q + f + 2);
        __builtin_nontemporal_store(x4.w + d3, out + OFF_Q + f + 3);
        local += d0 * d0 + d1 * d1 + d2 * d2 + d3 * d3;
    }
    // wave64 reduce
    for (int o = 32; o > 0; o >>= 1) local += __shfl_down(local, o);
    __shared__ float sm[4];
    const int lane = threadIdx.x & 63, wid = threadIdx.x >> 6;
    if (lane == 0) sm[wid] = local;
    __syncthreads();
    if (threadIdx.x == 0) {
        atomicAdd(acc, sm[0] + sm[1] + sm[2] + sm[3]);
    }
}

// Scatter the NSP ones into the (already-zeroed) encodings region, patch the 4
// edge elements the aligned memset skipped, and finalize loss + KL passthrough.
__global__ __launch_bounds__(256) void vq_scatter_fin(const int* __restrict__ x_tilde,
                                                      const float* __restrict__ acc,
                                                      const float* __restrict__ kl,
                                                      float* __restrict__ out) {
    const int bid = blockIdx.x;
    if (bid < NSP / 256) {
        const int n = (bid << 8) + threadIdx.x;
        const int t = x_tilde[n];
        out[OFF_ENC + (n << 10) + t] = 1.0f;
    } else {
        const int tt = threadIdx.x;
        if (tt < 32) out[1 + tt] = kl[tt];
        if (tt == 32) out[0] = 1.25f * (*acc) / (float)NTOT;
        // Patch the memset-skipped edges. Write (x_tilde==col) so a collision with
        // the scattered 1.0 for the same slot is a benign same-value race.
        if (tt == 33) {
            const int t0 = x_tilde[0];
            out[OFF_ENC + 0] = (t0 == 0) ? 1.f : 0.f;
            out[OFF_ENC + 1] = (t0 == 1) ? 1.f : 0.f;
            out[OFF_ENC + 2] = (t0 == 2) ? 1.f : 0.f;
            const int tl = x_tilde[NSP - 1];
            out[OFF_ENC + (int)ENC_ELEMS - 1] = (tl == 1023) ? 1.f : 0.f;
        }
    }
}

extern "C" void kernel_launch(void* const* d_in, const int* in_sizes, int n_in,
                              void* d_out, int out_size, void* d_ws, size_t ws_size,
                              hipStream_t stream) {
    const float* input1 = (const float*)d_in[0];
    const float* kl     = (const float*)d_in[1];
    const float* weight = (const float*)d_in[2];
    const int*   x_til  = (const int*)d_in[3];
    float* out = (float*)d_out;
    float* acc = (float*)d_ws;

    hipMemsetAsync(acc, 0, sizeof(float), stream);
    // Zero the 16B-ALIGNED interior of the 537 MB encodings region so rocclr's
    // fill takes the dwordx4 path (~6.5-6.9 TB/s measured) instead of the dword
    // path (1.55 TB/s measured in round 2). Edges patched in vq_scatter_fin.
    hipMemsetAsync(out + OFF_ENC + 3, 0, ENC_FILL_BYTES, stream);

    vq_main<<<2048, 256, 0, stream>>>(input1, x_til, weight, out, acc);
    vq_scatter_fin<<<NSP / 256 + 1, 256, 0, stream>>>(x_til, acc, kl, out);
}